// Round 13
// baseline (373.668 us; speedup 1.0000x reference)
//
#include <hip/hip_runtime.h>
#include <math.h>

#define GXD 128
#define GYD 128
#define GZD 32
#define DD  64
#define GCELLS (GXD * GYD * GZD)   // 524288

#define MINX (-20.0f)
#define MINY (-20.0f)
#define MINZ (-2.0f)
#define VOXX (0.3125f)
#define VOXY (0.3125f)
#define VOXZ (0.25f)
#define ELL  (0.5f)
#define EPSV (1e-6f)
#define PIF  (3.14159265358979323846f)

typedef float v2f __attribute__((ext_vector_type(2)));
typedef float v4f __attribute__((ext_vector_type(4)));

// Column weights: for the 9 (ox,oy) columns, w0 = kval at oz=0, w1 = kval at
// |oz|=1. Corners (|ox|=|oy|=1) have w1 == 0 (d >= ELL). c = (ox+1)*3+(oy+1).
struct KvCols { float w0[9]; float w1[9]; };
#define IS_PLUS(c) ((c) == 1 || (c) == 3 || (c) == 4 || (c) == 5 || (c) == 7)

// ---------------------------------------------------------------------------
__device__ __forceinline__ float kval_of(int o) {   // fallback path only
    int ox = o / 9 - 1;
    int oy = (o / 3) % 3 - 1;
    int oz = o % 3 - 1;
    float dx = ox * VOXX, dy = oy * VOXY, dz = oz * VOXZ;
    float d = sqrtf(dx * dx + dy * dy + dz * dz);
    float ang = 2.0f * PIF * d / ELL;
    float v = (1.0f / 3.0f) * (2.0f + cosf(ang)) * (1.0f - d / ELL)
            + (1.0f / (2.0f * PIF)) * sinf(ang);
    v = (d >= ELL) ? 0.0f : v;
    return fminf(fmaxf(v, 0.0f), 1.0f);
}

__device__ __forceinline__ int base_cell(const float* __restrict__ row,
                                         int* cx, int* cy, int* cz) {
    float x = row[0], y = row[1], z = row[2];
    int gx = (int)floorf((x - MINX) / VOXX);
    int gy = (int)floorf((y - MINY) / VOXY);
    int gz = (int)floorf((z - MINZ) / VOXZ);
    gx = min(max(gx, 0), GXD - 1);
    gy = min(max(gy, 0), GYD - 1);
    gz = min(max(gz, 0), GZD - 1);
    *cx = gx; *cy = gy; *cz = gz;
    return (gx * GYD + gy) * GZD + gz;
}

// ===========================================================================
// FAST PATH — workspace (floats):
//   M0 : [0, GCELLS)            cell counts (memset)
//   MM : PAIR-interleaved moments: for cell g, lane l:
//        byte = (g>>1)*1024 + l*16 + (g&1)*8 ; (m1, m2) at +0, +4.
//        One dwordx4 per lane = both planes of a z-pair.
//        + 2048-float zero sentinel pad at the end (sentp = pad + 2048B).
// ===========================================================================

// Pass 1: zero the full 16B pair row of each touched base cell (races benign)
__global__ void lbki_zero_rows(const float* __restrict__ pc,
                               float4* __restrict__ MM4,
                               int npts) {
    int lane = threadIdx.x & 63;
    int wave = threadIdx.x >> 6;
    int p = blockIdx.x * (blockDim.x >> 6) + wave;
    if (p >= npts) return;
    int cx, cy, cz;
    int g = base_cell(pc + (size_t)p * 67, &cx, &cy, &cz);
    MM4[(size_t)(g >> 1) * 64 + lane] = make_float4(0.f, 0.f, 0.f, 0.f);
}

// Pass 2: scatter per-point raw moments into the BASE cell only.
__global__ void lbki_build(const float* __restrict__ pc,
                           float* __restrict__ M0,
                           float* __restrict__ MM,
                           int npts) {
    int lane = threadIdx.x & 63;
    int wave = threadIdx.x >> 6;
    int p = blockIdx.x * (blockDim.x >> 6) + wave;
    if (p >= npts) return;
    const float* row = pc + (size_t)p * 67;
    int cx, cy, cz;
    int g = base_cell(row, &cx, &cy, &cz);
    float f = row[3 + lane];
    size_t e = (size_t)(g >> 1) * 256 + (size_t)lane * 4 + (size_t)(g & 1) * 2;
    atomicAdd(&MM[e],     f);
    atomicAdd(&MM[e + 1], f * f);
    if (lane == 0) atomicAdd(&M0[g], 1.0f);
}

// z-column stencil fused with finalize. Block = 8 adjacent y-columns (one
// wave each, lane = feature). Marches 2 cells (1 z-pair) per step.
// Per double-step t (cells 2t-2, 2t-1 finalized):
//   fin-even(2t-2) -> reduce pair(2t,2t+1) -> issue pair(2t+2,2t+3)
//   -> fin-odd(2t-1) -> prefetch maps(2t,2t+1)
// Slot algebra (ring of 4, cell&3): plane 2t scatters into cells 2t-1,2t,2t+1;
// plane 2t+1 into 2t,2t+1,2t+2. Cell 2t+2 shares slot with 2t-2: cleared by
// fin-even BEFORE the reduce writes it.
__global__ __launch_bounds__(512)
void lbki_stencil_col9(const float* __restrict__ M0,
                       const float* __restrict__ MM,
                       const float* __restrict__ mean_map,
                       const float* __restrict__ var_map,
                       const float* __restrict__ conf_map,
                       float* __restrict__ out_mean,
                       float* __restrict__ out_var,
                       float* __restrict__ out_conf,
                       KvCols ka) {
    __shared__ float    sm0[3 * 10 * 35];  // [xo][yo][zp], zp = z+1, pads zero
    __shared__ float    kb_lds[256];       // [col 0..7][z] precomputed k_bar
    __shared__ unsigned smask[30];         // per halo column: bit z = nonempty
    const int tid  = threadIdx.x;
    const int lane = tid & 63;
    const int wave = __builtin_amdgcn_readfirstlane(tid >> 6);

    // bijective XCD swizzle (2048 blocks, % 8 == 0)
    unsigned bid = blockIdx.x;
    unsigned chunk = gridDim.x >> 3;
    unsigned swz = (bid & 7u) * chunk + (bid >> 3);
    const int col0 = (int)(swz * 8u);
    const int cx  = col0 >> 7;
    const int cy0 = col0 & 127;

    // ---- stage M0 halo into LDS: sm0[xo][yo][z+1], zeros outside ----
    for (int e = tid; e < 3 * 10 * 35; e += 512) {
        int xo = e / 350;
        int r  = e - xo * 350;
        int yo = r / 35;
        int zp = r - yo * 35;
        int z  = zp - 1;
        int gx_ = cx - 1 + xo;
        int gy_ = cy0 - 1 + yo;
        bool v = ((unsigned)gx_ < (unsigned)GXD) &&
                 ((unsigned)gy_ < (unsigned)GYD) && ((unsigned)z < (unsigned)GZD);
        float val = 0.0f;
        if (v) val = M0[((gx_ << 7) + gy_) * 32 + z];
        sm0[e] = val;
    }
    __syncthreads();

    // ---- once per block: k_bar + out_conf for 256 cells + 30 masks ----
    if (tid < 256) {
        int j = tid >> 5, z = tid & 31;
        float kb = 0.0f;
        #pragma unroll
        for (int c = 0; c < 9; ++c) {
            const float* sc = sm0 + ((c / 3) * 10 + j + c % 3) * 35 + z + 1;
            kb += ka.w0[c] * sc[0];
            if (IS_PLUS(c)) kb += ka.w1[c] * (sc[-1] + sc[1]);
        }
        kb_lds[(j << 5) + z] = kb;
        unsigned cell = (unsigned)((cx << 7) + cy0 + j) * 32u + (unsigned)z;
        out_conf[cell] = conf_map[cell] + kb;
    } else if (tid < 256 + 30) {
        int idx = tid - 256;
        const float* sc = sm0 + idx * 35 + 1;
        unsigned m = 0;
        for (int z = 0; z < 32; ++z)
            if (sc[z] != 0.0f) m |= (1u << z);
        smask[idx] = m;
    }
    __syncthreads();

    // ---- per-wave setup (all wave-uniform -> SGPR) ----
    const int cy = cy0 + wave;
    const char* sentp = (const char*)MM + (size_t)GCELLS * 512u + 2048;

    unsigned long long mk[9];
    const char* tp[9];
    #pragma unroll
    for (int c = 0; c < 9; ++c) {
        unsigned mval = (unsigned)__builtin_amdgcn_readfirstlane(
                            (int)smask[(c / 3) * 10 + wave + c % 3]);
        mk[c] = (unsigned long long)mval;
        int nx = cx + c / 3 - 1;
        int ny = cy + c % 3 - 1;
        bool v = ((unsigned)nx < (unsigned)GXD) && ((unsigned)ny < (unsigned)GYD);
        tp[c] = v ? ((const char*)MM + (size_t)(((nx << 7) + ny) << 5) * 512u)
                  : sentp;
    }
    const int laneB = lane * 16;

    const unsigned gbase = (unsigned)((cx << 7) + cy) * 32u;
    unsigned rb = (gbase * 64u + (unsigned)lane) * 4u;   // row byte, z=0
    unsigned gb = gbase * 4u;

    const char* MEc = (const char*)mean_map;
    const char* VAc = (const char*)var_map;
    const char* COc = (const char*)conf_map;
    char*       OMc = (char*)out_mean;
    char*       OVc = (char*)out_var;

    v2f ysw[4];
    #pragma unroll
    for (int s = 0; s < 4; ++s) ysw[s] = (v2f)0.0f;
    v4f inf[9];
    float mbuf[2], vbuf[2], cbuf[2];
    const float* kbp = kb_lds + (wave << 5);

#define REDUCE_T0T1                                                    \
    v4f t0 = (v4f)0.0f, t1 = (v4f)0.0f;                                \
    _Pragma("unroll")                                                  \
    for (int c = 0; c < 9; ++c) {                                      \
        t0 += inf[c] * ka.w0[c];                                       \
        if (IS_PLUS(c)) t1 += inf[c] * ka.w1[c];                       \
    }                                                                  \
    v2f y0e, y0o, y1e, y1o;                                            \
    y0e.x = t0.x; y0e.y = t0.y; y0o.x = t0.z; y0o.y = t0.w;            \
    y1e.x = t1.x; y1e.y = t1.y; y1o.x = t1.z; y1o.y = t1.w;

#define FIN(slot, kbv, mi, storeOff)                                   \
    {                                                                  \
        float mean = mbuf[mi], var = vbuf[mi], conf = cbuf[mi];        \
        float kb   = (kbv);                                            \
        v2f   w    = ysw[slot];                                        \
        float rin  = __builtin_amdgcn_rcpf(kb + EPSV);                 \
        float ybar = w.x * rin;                                        \
        float Sbar = w.y - 2.0f * ybar * w.x + ybar * ybar * kb;       \
        float rden = __builtin_amdgcn_rcpf(conf + kb + EPSV);          \
        float dm   = ybar - mean;                                      \
        float scal = conf * kb * rden;                                 \
        __builtin_nontemporal_store((conf * mean + kb * ybar) * rden,  \
                                    (float*)(OMc + rb + (storeOff)));  \
        __builtin_nontemporal_store(var + Sbar + scal * dm * dm,       \
                                    (float*)(OVc + rb + (storeOff)));  \
        ysw[slot] = (v2f)0.0f;                                         \
    }

    // ---- prologue: pair 0 (planes 0,1) ----
    #pragma unroll
    for (int c = 0; c < 9; ++c) {
        const char* p = (mk[c] & 3ull) ? tp[c] : sentp;
        inf[c] = *(const v4f*)(p + laneB);
    }
    {   // reduce pair 0 — plane 0's down-scatter (cell -1) dropped
        REDUCE_T0T1
        ysw[0] += y0e + y1o;
        ysw[1] += y1e + y0o;
        ysw[2] += y1o;
    }
    // issue pair 1 (planes 2,3)
    #pragma unroll
    for (int c = 0; c < 9; ++c) {
        const char* p = ((mk[c] >> 2) & 3ull) ? tp[c] : sentp;
        inf[c] = *(const v4f*)(p + laneB + 1024);
    }
    // maps cells 0,1
    mbuf[0] = __builtin_nontemporal_load((const float*)(MEc + rb));
    vbuf[0] = __builtin_nontemporal_load((const float*)(VAc + rb));
    cbuf[0] = *(const float*)(COc + gb);
    mbuf[1] = __builtin_nontemporal_load((const float*)(MEc + rb + 256));
    vbuf[1] = __builtin_nontemporal_load((const float*)(VAc + rb + 256));
    cbuf[1] = *(const float*)(COc + gb + 4);
    #pragma unroll
    for (int c = 0; c < 9; ++c) tp[c] += 4096;

    // ---- main loop: zb = 0..2, k = 0..3  (double-steps t' = 4zb+k+1) ----
    for (int zb = 0; zb < 3; ++zb) {
        #pragma unroll
        for (int k = 0; k < 4; ++k) {
            float2 kb2 = *(const float2*)(kbp + 2 * k);

            // finalize EVEN cell 2t'-2 (slot (2k)&3) — clears the slot that
            // this step's reduce re-targets as cell 2t'+2
            FIN((2 * k) & 3, kb2.x, 0, (2 * k) * 256)

            // reduce pair (2t', 2t'+1)  [issued last step]
            {
                REDUCE_T0T1
                ysw[(2 * k + 1) & 3] += y1e;
                ysw[(2 * k + 2) & 3] += y0e + y1o;
                ysw[(2 * k + 3) & 3] += y1e + y0o;
                ysw[(2 * k + 0) & 3] += y1o;
            }

            // issue pair t'+1 (planes 2t'+2, 2t'+3); scalar 2-bit gate
            #pragma unroll
            for (int c = 0; c < 9; ++c) {
                const char* p = ((mk[c] >> (2 * k + 4)) & 3ull) ? tp[c] : sentp;
                inf[c] = *(const v4f*)(p + laneB + (k - 2) * 1024);
            }

            // finalize ODD cell 2t'-1 (slot (2k+1)&3)
            FIN((2 * k + 1) & 3, kb2.y, 1, (2 * k + 1) * 256)

            // prefetch maps cells 2t', 2t'+1
            mbuf[0] = __builtin_nontemporal_load((const float*)(MEc + rb + (2 * k + 2) * 256));
            vbuf[0] = __builtin_nontemporal_load((const float*)(VAc + rb + (2 * k + 2) * 256));
            cbuf[0] = *(const float*)(COc + gb + (2 * k + 2) * 4);
            mbuf[1] = __builtin_nontemporal_load((const float*)(MEc + rb + (2 * k + 3) * 256));
            vbuf[1] = __builtin_nontemporal_load((const float*)(VAc + rb + (2 * k + 3) * 256));
            cbuf[1] = *(const float*)(COc + gb + (2 * k + 3) * 4);
        }
        rb += 2048u; gb += 32u; kbp += 8;
        #pragma unroll
        for (int c = 0; c < 9; ++c) { tp[c] += 4096; mk[c] >>= 8; }
    }

    // ---- tail: t' = 13..16 (zb = 3 unrolled; no issue at k=2, no reduce/
    //      prefetch at k=3) ----
    #pragma unroll
    for (int k = 0; k < 4; ++k) {
        float2 kb2 = *(const float2*)(kbp + 2 * k);
        FIN((2 * k) & 3, kb2.x, 0, (2 * k) * 256)
        if (k < 3) {
            REDUCE_T0T1
            ysw[(2 * k + 1) & 3] += y1e;
            ysw[(2 * k + 2) & 3] += y0e + y1o;
            ysw[(2 * k + 3) & 3] += y1e + y0o;
            ysw[(2 * k + 0) & 3] += y1o;
            if (k < 2) {
                #pragma unroll
                for (int c = 0; c < 9; ++c) {
                    const char* p = ((mk[c] >> (2 * k + 4)) & 3ull) ? tp[c] : sentp;
                    inf[c] = *(const v4f*)(p + laneB + (k - 2) * 1024);
                }
            }
        }
        FIN((2 * k + 1) & 3, kb2.y, 1, (2 * k + 1) * 256)
        if (k < 3) {
            mbuf[0] = __builtin_nontemporal_load((const float*)(MEc + rb + (2 * k + 2) * 256));
            vbuf[0] = __builtin_nontemporal_load((const float*)(VAc + rb + (2 * k + 2) * 256));
            cbuf[0] = *(const float*)(COc + gb + (2 * k + 2) * 4);
            mbuf[1] = __builtin_nontemporal_load((const float*)(MEc + rb + (2 * k + 3) * 256));
            vbuf[1] = __builtin_nontemporal_load((const float*)(VAc + rb + (2 * k + 3) * 256));
            cbuf[1] = *(const float*)(COc + gb + (2 * k + 3) * 4);
        }
    }
#undef FIN
#undef REDUCE_T0T1
}

// ===========================================================================
// FALLBACK PATH (round-1 kernels, used only if workspace is too small)
// ===========================================================================
__global__ void lbki_accum(const float* __restrict__ pc,
                           float* __restrict__ y_sum,
                           float* __restrict__ sq_sum,
                           float* __restrict__ k_bar,
                           int npts) {
    __shared__ float kval_s[27];
    if (threadIdx.x < 27) kval_s[threadIdx.x] = kval_of(threadIdx.x);
    __syncthreads();

    int lane = threadIdx.x & 63;
    int wave = threadIdx.x >> 6;
    int p = blockIdx.x * (blockDim.x >> 6) + wave;
    if (p >= npts) return;

    const float* row = pc + (size_t)p * 67;
    int gx, gy, gz;
    base_cell(row, &gx, &gy, &gz);
    float f = row[3 + lane];
    float ff = f * f;

    #pragma unroll
    for (int o = 0; o < 27; ++o) {
        float kv = kval_s[o];
        if (kv <= 0.0f) continue;
        int nx = gx + (o / 9) - 1;
        int ny = gy + ((o / 3) % 3) - 1;
        int nz = gz + (o % 3) - 1;
        if ((unsigned)nx >= (unsigned)GXD) continue;
        if ((unsigned)ny >= (unsigned)GYD) continue;
        if ((unsigned)nz >= (unsigned)GZD) continue;
        size_t g = ((size_t)nx * GYD + ny) * GZD + nz;
        atomicAdd(&y_sum[g * DD + lane], kv * f);
        atomicAdd(&sq_sum[g * DD + lane], kv * ff);
        if (lane == 0) atomicAdd(&k_bar[g], kv);
    }
}

__global__ void lbki_finalize(const float* __restrict__ mean_map,
                              const float* __restrict__ var_map,
                              const float* __restrict__ conf_map,
                              float* __restrict__ out_mean,
                              float* __restrict__ out_var,
                              float* __restrict__ out_conf) {
    int lane = threadIdx.x & 63;
    int wave = threadIdx.x >> 6;
    int g = blockIdx.x * (blockDim.x >> 6) + wave;
    if (g >= GCELLS) return;

    float kb   = out_conf[g];
    float conf = conf_map[g];

    size_t idx = (size_t)g * DD + lane;
    float ys   = out_mean[idx];
    float sq   = out_var[idx];
    float mean = mean_map[idx];
    float var  = var_map[idx];

    float ybar  = ys / (kb + EPSV);
    float Sbar  = sq - 2.0f * ybar * ys + ybar * ybar * kb;
    float denom = conf + kb + EPSV;
    float dm    = ybar - mean;
    float scal  = conf * kb / denom;

    out_mean[idx] = (conf * mean + kb * ybar) / denom;
    out_var[idx]  = var + Sbar + scal * dm * dm;
    if (lane == 0) out_conf[g] = conf + kb;
}

// ===========================================================================
extern "C" void kernel_launch(void* const* d_in, const int* in_sizes, int n_in,
                              void* d_out, int out_size, void* d_ws, size_t ws_size,
                              hipStream_t stream) {
    const float* mean_map = (const float*)d_in[0];
    const float* var_map  = (const float*)d_in[1];
    const float* conf_map = (const float*)d_in[2];
    const float* pc       = (const float*)d_in[3];
    int npts = in_sizes[3] / 67;

    float* out      = (float*)d_out;
    float* out_mean = out;
    float* out_var  = out + (size_t)GCELLS * DD;
    float* out_conf = out + (size_t)2 * GCELLS * DD;

    const size_t M0_ELEMS = (size_t)GCELLS;
    const size_t MM_ELEMS = (size_t)GCELLS * 128 + 2048;   // + 8KB sentinel pad
    const size_t WS_NEEDED = (M0_ELEMS + MM_ELEMS) * sizeof(float);

    if (ws_size >= WS_NEEDED) {
        float* M0 = (float*)d_ws;
        float* MM = M0 + M0_ELEMS;

        // small zeroing only: counts (2MB) + sentinel pad (8KB)
        hipMemsetAsync(M0, 0, M0_ELEMS * sizeof(float), stream);
        hipMemsetAsync(MM + (size_t)GCELLS * 128, 0, 2048 * sizeof(float), stream);

        int wpb = 4;
        int pblocks = (npts + wpb - 1) / wpb;
        lbki_zero_rows<<<pblocks, 256, 0, stream>>>(pc, (float4*)MM, npts);
        lbki_build<<<pblocks, 256, 0, stream>>>(pc, M0, MM, npts);

        // host-side column weights (double precision, cast to f32)
        KvCols ka;
        for (int c = 0; c < 9; ++c) {
            int ox = c / 3 - 1, oy = c % 3 - 1;
            for (int k = 0; k < 2; ++k) {   // k = |oz|
                double dx = ox * (double)VOXX;
                double dy = oy * (double)VOXY;
                double dz = k  * (double)VOXZ;
                double d  = sqrt(dx * dx + dy * dy + dz * dz);
                double ang = 2.0 * (double)PIF * d / (double)ELL;
                double v = (1.0 / 3.0) * (2.0 + cos(ang)) * (1.0 - d / (double)ELL)
                         + (1.0 / (2.0 * (double)PIF)) * sin(ang);
                if (d >= (double)ELL) v = 0.0;
                v = v < 0.0 ? 0.0 : (v > 1.0 ? 1.0 : v);
                if (k == 0) ka.w0[c] = (float)v; else ka.w1[c] = (float)v;
            }
        }

        int sblocks = (GXD * GYD) / 8;   // 2048 blocks, % 8 == 0
        lbki_stencil_col9<<<sblocks, 512, 0, stream>>>(M0, MM,
                                                       mean_map, var_map, conf_map,
                                                       out_mean, out_var, out_conf,
                                                       ka);
    } else {
        hipMemsetAsync(d_out, 0, (size_t)out_size * sizeof(float), stream);
        int wpb = 4;
        int blocks = (npts + wpb - 1) / wpb;
        lbki_accum<<<blocks, 256, 0, stream>>>(pc, out_mean, out_var, out_conf, npts);
        int fblocks = GCELLS / 4;
        lbki_finalize<<<fblocks, 256, 0, stream>>>(mean_map, var_map, conf_map,
                                                   out_mean, out_var, out_conf);
    }
}

// Round 14
// 307.331 us; speedup vs baseline: 1.2158x; 1.2158x over previous
//
#include <hip/hip_runtime.h>
#include <math.h>

#define GXD 128
#define GYD 128
#define GZD 32
#define DD  64
#define GCELLS (GXD * GYD * GZD)   // 524288

#define MINX (-20.0f)
#define MINY (-20.0f)
#define MINZ (-2.0f)
#define VOXX (0.3125f)
#define VOXY (0.3125f)
#define VOXZ (0.25f)
#define ELL  (0.5f)
#define EPSV (1e-6f)
#define PIF  (3.14159265358979323846f)

typedef float v2f __attribute__((ext_vector_type(2)));
typedef float v4f __attribute__((ext_vector_type(4)));

// Column weights: for the 9 (ox,oy) columns, w0 = kval at oz=0, w1 = kval at
// |oz|=1. Corners (|ox|=|oy|=1) have w1 == 0 (d >= ELL). c = (ox+1)*3+(oy+1).
struct KvCols { float w0[9]; float w1[9]; };
#define IS_PLUS(c) ((c) == 1 || (c) == 3 || (c) == 4 || (c) == 5 || (c) == 7)

// ---------------------------------------------------------------------------
__device__ __forceinline__ float kval_of(int o) {   // fallback path only
    int ox = o / 9 - 1;
    int oy = (o / 3) % 3 - 1;
    int oz = o % 3 - 1;
    float dx = ox * VOXX, dy = oy * VOXY, dz = oz * VOXZ;
    float d = sqrtf(dx * dx + dy * dy + dz * dz);
    float ang = 2.0f * PIF * d / ELL;
    float v = (1.0f / 3.0f) * (2.0f + cosf(ang)) * (1.0f - d / ELL)
            + (1.0f / (2.0f * PIF)) * sinf(ang);
    v = (d >= ELL) ? 0.0f : v;
    return fminf(fmaxf(v, 0.0f), 1.0f);
}

__device__ __forceinline__ int base_cell(const float* __restrict__ row,
                                         int* cx, int* cy, int* cz) {
    float x = row[0], y = row[1], z = row[2];
    int gx = (int)floorf((x - MINX) / VOXX);
    int gy = (int)floorf((y - MINY) / VOXY);
    int gz = (int)floorf((z - MINZ) / VOXZ);
    gx = min(max(gx, 0), GXD - 1);
    gy = min(max(gy, 0), GYD - 1);
    gz = min(max(gz, 0), GZD - 1);
    *cx = gx; *cy = gy; *cz = gz;
    return (gx * GYD + gy) * GZD + gz;
}

// ===========================================================================
// FAST PATH — workspace (floats), FLAT layout (compact atomics):
//   M0 : [0, GCELLS)            cell counts (memset)
//   MM : [cell][feature][m1,m2] = 512B/cell; + 8192-float zero sentinel pad
//        (stencil reads dwordx4 at pairBase + lane*16: lanes 0-31 = even
//         cell's features 2l,2l+1; lanes 32-63 = odd cell's — no interleave
//         needed, 64 lanes x 16B = exactly 2 rows)
// ===========================================================================

// Pass 1: zero own row AND partner row of the z-pair (a pair is gathered if
// EITHER cell is occupied, so the empty partner must be zeroed too; races
// benign: everyone writes zeros, before build)
__global__ void lbki_zero_rows(const float* __restrict__ pc,
                               float2* __restrict__ MM2,
                               int npts) {
    int lane = threadIdx.x & 63;
    int wave = threadIdx.x >> 6;
    int p = blockIdx.x * (blockDim.x >> 6) + wave;
    if (p >= npts) return;
    int cx, cy, cz;
    int g = base_cell(pc + (size_t)p * 67, &cx, &cy, &cz);
    MM2[(size_t)g * DD + lane]       = make_float2(0.0f, 0.0f);
    MM2[(size_t)(g ^ 1) * DD + lane] = make_float2(0.0f, 0.0f);
}

// Pass 2: compact scatter (R12 addressing — 8B stride per lane)
__global__ void lbki_build(const float* __restrict__ pc,
                           float* __restrict__ M0,
                           float* __restrict__ MM,
                           int npts) {
    int lane = threadIdx.x & 63;
    int wave = threadIdx.x >> 6;
    int p = blockIdx.x * (blockDim.x >> 6) + wave;
    if (p >= npts) return;
    const float* row = pc + (size_t)p * 67;
    int cx, cy, cz;
    int g = base_cell(row, &cx, &cy, &cz);
    float f = row[3 + lane];
    size_t e = ((size_t)g * DD + lane) * 2;
    atomicAdd(&MM[e],     f);
    atomicAdd(&MM[e + 1], f * f);
    if (lane == 0) atomicAdd(&M0[g], 1.0f);
}

// z-column stencil fused with finalize. Block = 8 adjacent y-columns, one
// wave each. LANE-SPLIT: lanes 0-31 own even-z cells (features 2l,2l+1 each),
// lanes 32-63 own odd-z. One z-pair per step; w1 cross-parity terms exchanged
// with one shfl_xor(32) of the 4-dword partial:
//   cell_even(2t)  = t0 + recv[t] + recv[t-1]
//   cell_odd(2t+1) = t0 + recv[t] + recv[t+1]   (finalized at step t+1)
__global__ __launch_bounds__(512)
void lbki_stencil_colA(const float* __restrict__ M0,
                       const float* __restrict__ MM,
                       const float* __restrict__ mean_map,
                       const float* __restrict__ var_map,
                       const float* __restrict__ conf_map,
                       float* __restrict__ out_mean,
                       float* __restrict__ out_var,
                       float* __restrict__ out_conf,
                       KvCols ka) {
    __shared__ float    sm0[3 * 10 * 35];  // [xo][yo][zp], zp = z+1, pads zero
    __shared__ float    kb_lds[256];       // [col 0..7][z] precomputed k_bar
    __shared__ unsigned smask[30];         // per halo column: bit z = nonempty
    const int tid  = threadIdx.x;
    const int lane = tid & 63;
    const int wave = __builtin_amdgcn_readfirstlane(tid >> 6);
    const int half = lane >> 5;            // 0: even-z cells, 1: odd-z cells
    const int l5   = lane & 31;

    // bijective XCD swizzle (2048 blocks, % 8 == 0)
    unsigned bid = blockIdx.x;
    unsigned chunk = gridDim.x >> 3;
    unsigned swz = (bid & 7u) * chunk + (bid >> 3);
    const int col0 = (int)(swz * 8u);
    const int cx  = col0 >> 7;
    const int cy0 = col0 & 127;

    // ---- stage M0 halo into LDS: sm0[xo][yo][z+1], zeros outside ----
    for (int e = tid; e < 3 * 10 * 35; e += 512) {
        int xo = e / 350;
        int r  = e - xo * 350;
        int yo = r / 35;
        int zp = r - yo * 35;
        int z  = zp - 1;
        int gx_ = cx - 1 + xo;
        int gy_ = cy0 - 1 + yo;
        bool v = ((unsigned)gx_ < (unsigned)GXD) &&
                 ((unsigned)gy_ < (unsigned)GYD) && ((unsigned)z < (unsigned)GZD);
        float val = 0.0f;
        if (v) val = M0[((gx_ << 7) + gy_) * 32 + z];
        sm0[e] = val;
    }
    __syncthreads();

    // ---- once per block: k_bar + out_conf for 256 cells + 30 masks ----
    if (tid < 256) {
        int j = tid >> 5, z = tid & 31;
        float kb = 0.0f;
        #pragma unroll
        for (int c = 0; c < 9; ++c) {
            const float* sc = sm0 + ((c / 3) * 10 + j + c % 3) * 35 + z + 1;
            kb += ka.w0[c] * sc[0];
            if (IS_PLUS(c)) kb += ka.w1[c] * (sc[-1] + sc[1]);
        }
        kb_lds[(j << 5) + z] = kb;
        unsigned cell = (unsigned)((cx << 7) + cy0 + j) * 32u + (unsigned)z;
        out_conf[cell] = conf_map[cell] + kb;
    } else if (tid < 256 + 30) {
        int idx = tid - 256;
        const float* sc = sm0 + idx * 35 + 1;
        unsigned m = 0;
        for (int z = 0; z < 32; ++z)
            if (sc[z] != 0.0f) m |= (1u << z);
        smask[idx] = m;
    }
    __syncthreads();

    // ---- per-wave setup (wave-uniform -> SGPR) ----
    const int cy = cy0 + wave;
    const char* sentp = (const char*)MM + (size_t)GCELLS * 512u;  // 32KB pad

    unsigned long long mk[9];
    const char* tp[9];
    #pragma unroll
    for (int c = 0; c < 9; ++c) {
        unsigned mval = (unsigned)__builtin_amdgcn_readfirstlane(
                            (int)smask[(c / 3) * 10 + wave + c % 3]);
        mk[c] = (unsigned long long)mval;
        int nx = cx + c / 3 - 1;
        int ny = cy + c % 3 - 1;
        bool v = ((unsigned)nx < (unsigned)GXD) && ((unsigned)ny < (unsigned)GYD);
        tp[c] = v ? ((const char*)MM + (size_t)(((nx << 7) + ny) << 5) * 512u)
                  : sentp;
    }
    const int laneB = lane * 16;

    const unsigned gbase = (unsigned)((cx << 7) + cy) * 32u;
    const int rowB  = (int)(gbase * 256u) + l5 * 8;       // cell0 maps row
    const int mapsB = rowB - half * 256;                  // cell(2t-half) @t=0
    const unsigned gb = gbase * 4u;

    const char* MEc = (const char*)mean_map;
    const char* VAc = (const char*)var_map;
    const char* COc = (const char*)conf_map;
    char*       OMc = (char*)out_mean;
    char*       OVc = (char*)out_var;
    const float* kbp = kb_lds + (wave << 5);

    v4f inf[9];
    v4f H = (v4f)0.0f, Hp = (v4f)0.0f, recv = (v4f)0.0f, Rp = (v4f)0.0f;
    v2f mb[2], vb[2];
    float cb[2];

#define REDUCE(T0, T1)                                                  \
    v4f T0 = (v4f)0.0f, T1 = (v4f)0.0f;                                 \
    _Pragma("unroll")                                                   \
    for (int c = 0; c < 9; ++c) {                                       \
        T0 += inf[c] * ka.w0[c];                                        \
        if (IS_PLUS(c)) T1 += inf[c] * ka.w1[c];                        \
    }

#define SWAP32(DST, SRC)                                                \
    DST.x = __shfl_xor(SRC.x, 32, 64);                                  \
    DST.y = __shfl_xor(SRC.y, 32, 64);                                  \
    DST.z = __shfl_xor(SRC.z, 32, 64);                                  \
    DST.w = __shfl_xor(SRC.w, 32, 64);

#define FINSTORE(W, KB, MB, VB, CB, ADDR)                               \
    {                                                                   \
        float kb_  = (KB);                                              \
        float cf_  = (CB);                                              \
        float rin  = __builtin_amdgcn_rcpf(kb_ + EPSV);                 \
        float rden = __builtin_amdgcn_rcpf(cf_ + kb_ + EPSV);           \
        float scal = cf_ * kb_ * rden;                                  \
        float ya = (W).x * rin, yb = (W).z * rin;                       \
        float Sa = (W).y - 2.0f * ya * (W).x + ya * ya * kb_;           \
        float Sb = (W).w - 2.0f * yb * (W).z + yb * yb * kb_;           \
        float da = ya - (MB).x, db = yb - (MB).y;                       \
        v2f om, ov;                                                     \
        om.x = (cf_ * (MB).x + kb_ * ya) * rden;                        \
        om.y = (cf_ * (MB).y + kb_ * yb) * rden;                        \
        ov.x = (VB).x + Sa + scal * da * da;                            \
        ov.y = (VB).y + Sb + scal * db * db;                            \
        __builtin_nontemporal_store(om, (v2f*)(OMc + (ADDR)));          \
        __builtin_nontemporal_store(ov, (v2f*)(OVc + (ADDR)));          \
    }

    // ---- prologue: load pair 0; maps for t=0 (cell0 row both halves), t=1 ----
    #pragma unroll
    for (int c = 0; c < 9; ++c) {
        const char* p = (mk[c] & 3ull) ? tp[c] : sentp;
        inf[c] = *(const v4f*)(p + laneB);
    }
    mb[0] = __builtin_nontemporal_load((const v2f*)(MEc + rowB));
    vb[0] = __builtin_nontemporal_load((const v2f*)(VAc + rowB));
    cb[0] = *(const float*)(COc + gb);
    mb[1] = __builtin_nontemporal_load((const v2f*)(MEc + mapsB + 512));
    vb[1] = __builtin_nontemporal_load((const v2f*)(VAc + mapsB + 512));
    cb[1] = *(const float*)(COc + gb + 8 - half * 4);

    // ---- peel t = 0: even half finalizes cell 0 ----
    {
        REDUCE(t0, t1)
        #pragma unroll
        for (int c = 0; c < 9; ++c) {   // issue pair 1
            const char* p = ((mk[c] >> 2) & 3ull) ? tp[c] : sentp;
            inf[c] = *(const v4f*)(p + laneB + 1024);
        }
        SWAP32(recv, t1)
        H = t0 + recv;
        if (!half) {
            FINSTORE(H, kbp[0], mb[0], vb[0], cb[0], rowB)
        }
        Hp = H; Rp = recv;
        // prefetch maps t=2 into buf0
        mb[0] = __builtin_nontemporal_load((const v2f*)(MEc + mapsB + 1024));
        vb[0] = __builtin_nontemporal_load((const v2f*)(VAc + mapsB + 1024));
        cb[0] = *(const float*)(COc + gb + 16 - half * 4);
    }

    // ---- main: t = 1..15 fully unrolled ----
    #pragma unroll
    for (int t = 1; t <= 15; ++t) {
        REDUCE(t0, t1)
        if (t < 15) {
            #pragma unroll
            for (int c = 0; c < 9; ++c) {   // issue pair t+1
                const char* p = ((mk[c] >> (2 * t + 2)) & 3ull) ? tp[c] : sentp;
                inf[c] = *(const v4f*)(p + laneB + (t + 1) * 1024);
            }
        }
        SWAP32(recv, t1)
        H = t0 + recv;
        // even: cell 2t = H + recv[t-1]; odd: cell 2t-1 = Hp + recv[t]
        v4f finv = half ? (Hp + recv) : (H + Rp);
        float kbv = kbp[2 * t - half];
        FINSTORE(finv, kbv, mb[t & 1], vb[t & 1], cb[t & 1], mapsB + t * 512)
        Hp = H; Rp = recv;
        if (t < 15) {   // prefetch maps t+1
            mb[(t + 1) & 1] = __builtin_nontemporal_load((const v2f*)(MEc + mapsB + (t + 1) * 512));
            vb[(t + 1) & 1] = __builtin_nontemporal_load((const v2f*)(VAc + mapsB + (t + 1) * 512));
            cb[(t + 1) & 1] = *(const float*)(COc + gb + (t + 1) * 8 - half * 4);
        } else {        // prefetch t=16 (clamped; only odd half's value used)
            int a16 = min(mapsB + 16 * 512, rowB + 31 * 256);
            mb[0] = __builtin_nontemporal_load((const v2f*)(MEc + a16));
            vb[0] = __builtin_nontemporal_load((const v2f*)(VAc + a16));
            cb[0] = *(const float*)(COc + min(gb + 128u - (unsigned)(half * 4), gb + 124u));
        }
    }

    // ---- epilogue t = 16: odd half finalizes cell 31 (recv[16] = 0) ----
    if (half) {
        FINSTORE(Hp, kbp[31], mb[0], vb[0], cb[0], mapsB + 16 * 512)
    }
#undef FINSTORE
#undef SWAP32
#undef REDUCE
}

// ===========================================================================
// FALLBACK PATH (round-1 kernels, used only if workspace is too small)
// ===========================================================================
__global__ void lbki_accum(const float* __restrict__ pc,
                           float* __restrict__ y_sum,
                           float* __restrict__ sq_sum,
                           float* __restrict__ k_bar,
                           int npts) {
    __shared__ float kval_s[27];
    if (threadIdx.x < 27) kval_s[threadIdx.x] = kval_of(threadIdx.x);
    __syncthreads();

    int lane = threadIdx.x & 63;
    int wave = threadIdx.x >> 6;
    int p = blockIdx.x * (blockDim.x >> 6) + wave;
    if (p >= npts) return;

    const float* row = pc + (size_t)p * 67;
    int gx, gy, gz;
    base_cell(row, &gx, &gy, &gz);
    float f = row[3 + lane];
    float ff = f * f;

    #pragma unroll
    for (int o = 0; o < 27; ++o) {
        float kv = kval_s[o];
        if (kv <= 0.0f) continue;
        int nx = gx + (o / 9) - 1;
        int ny = gy + ((o / 3) % 3) - 1;
        int nz = gz + (o % 3) - 1;
        if ((unsigned)nx >= (unsigned)GXD) continue;
        if ((unsigned)ny >= (unsigned)GYD) continue;
        if ((unsigned)nz >= (unsigned)GZD) continue;
        size_t g = ((size_t)nx * GYD + ny) * GZD + nz;
        atomicAdd(&y_sum[g * DD + lane], kv * f);
        atomicAdd(&sq_sum[g * DD + lane], kv * ff);
        if (lane == 0) atomicAdd(&k_bar[g], kv);
    }
}

__global__ void lbki_finalize(const float* __restrict__ mean_map,
                              const float* __restrict__ var_map,
                              const float* __restrict__ conf_map,
                              float* __restrict__ out_mean,
                              float* __restrict__ out_var,
                              float* __restrict__ out_conf) {
    int lane = threadIdx.x & 63;
    int wave = threadIdx.x >> 6;
    int g = blockIdx.x * (blockDim.x >> 6) + wave;
    if (g >= GCELLS) return;

    float kb   = out_conf[g];
    float conf = conf_map[g];

    size_t idx = (size_t)g * DD + lane;
    float ys   = out_mean[idx];
    float sq   = out_var[idx];
    float mean = mean_map[idx];
    float var  = var_map[idx];

    float ybar  = ys / (kb + EPSV);
    float Sbar  = sq - 2.0f * ybar * ys + ybar * ybar * kb;
    float denom = conf + kb + EPSV;
    float dm    = ybar - mean;
    float scal  = conf * kb / denom;

    out_mean[idx] = (conf * mean + kb * ybar) / denom;
    out_var[idx]  = var + Sbar + scal * dm * dm;
    if (lane == 0) out_conf[g] = conf + kb;
}

// ===========================================================================
extern "C" void kernel_launch(void* const* d_in, const int* in_sizes, int n_in,
                              void* d_out, int out_size, void* d_ws, size_t ws_size,
                              hipStream_t stream) {
    const float* mean_map = (const float*)d_in[0];
    const float* var_map  = (const float*)d_in[1];
    const float* conf_map = (const float*)d_in[2];
    const float* pc       = (const float*)d_in[3];
    int npts = in_sizes[3] / 67;

    float* out      = (float*)d_out;
    float* out_mean = out;
    float* out_var  = out + (size_t)GCELLS * DD;
    float* out_conf = out + (size_t)2 * GCELLS * DD;

    const size_t M0_ELEMS = (size_t)GCELLS;
    const size_t MM_ELEMS = (size_t)GCELLS * 128 + 8192;   // + 32KB sentinel
    const size_t WS_NEEDED = (M0_ELEMS + MM_ELEMS) * sizeof(float);

    if (ws_size >= WS_NEEDED) {
        float* M0 = (float*)d_ws;
        float* MM = M0 + M0_ELEMS;

        // small zeroing only: counts (2MB) + sentinel pad (32KB)
        hipMemsetAsync(M0, 0, M0_ELEMS * sizeof(float), stream);
        hipMemsetAsync(MM + (size_t)GCELLS * 128, 0, 8192 * sizeof(float), stream);

        int wpb = 4;
        int pblocks = (npts + wpb - 1) / wpb;
        lbki_zero_rows<<<pblocks, 256, 0, stream>>>(pc, (float2*)MM, npts);
        lbki_build<<<pblocks, 256, 0, stream>>>(pc, M0, MM, npts);

        // host-side column weights (double precision, cast to f32)
        KvCols ka;
        for (int c = 0; c < 9; ++c) {
            int ox = c / 3 - 1, oy = c % 3 - 1;
            for (int k = 0; k < 2; ++k) {   // k = |oz|
                double dx = ox * (double)VOXX;
                double dy = oy * (double)VOXY;
                double dz = k  * (double)VOXZ;
                double d  = sqrt(dx * dx + dy * dy + dz * dz);
                double ang = 2.0 * (double)PIF * d / (double)ELL;
                double v = (1.0 / 3.0) * (2.0 + cos(ang)) * (1.0 - d / (double)ELL)
                         + (1.0 / (2.0 * (double)PIF)) * sin(ang);
                if (d >= (double)ELL) v = 0.0;
                v = v < 0.0 ? 0.0 : (v > 1.0 ? 1.0 : v);
                if (k == 0) ka.w0[c] = (float)v; else ka.w1[c] = (float)v;
            }
        }

        int sblocks = (GXD * GYD) / 8;   // 2048 blocks, % 8 == 0
        lbki_stencil_colA<<<sblocks, 512, 0, stream>>>(M0, MM,
                                                       mean_map, var_map, conf_map,
                                                       out_mean, out_var, out_conf,
                                                       ka);
    } else {
        hipMemsetAsync(d_out, 0, (size_t)out_size * sizeof(float), stream);
        int wpb = 4;
        int blocks = (npts + wpb - 1) / wpb;
        lbki_accum<<<blocks, 256, 0, stream>>>(pc, out_mean, out_var, out_conf, npts);
        int fblocks = GCELLS / 4;
        lbki_finalize<<<fblocks, 256, 0, stream>>>(mean_map, var_map, conf_map,
                                                   out_mean, out_var, out_conf);
    }
}